// Round 7
// baseline (276.737 us; speedup 1.0000x reference)
//
#include <hip/hip_runtime.h>
#include <hip/hip_bf16.h>
#include <stdint.h>

#define BATCH 16
#define CIN   512
#define COUT  512
#define HH    32
#define WW    32
#define HP    34
#define HWN   1024
#define EPS_  1e-8f

#define NTILES 72            // 9 taps * 8 ic-chunks, BK=64
#define SLOTB  32768         // 256 rows * 128 B
#define LDS_BYTES (3*SLOTB)  // 96 KB, B-only

typedef __attribute__((ext_vector_type(8))) short bf16x8;
typedef __attribute__((ext_vector_type(4))) float f32x4;
typedef __attribute__((address_space(1))) void gvoid;
typedef __attribute__((address_space(3))) void lvoid;

// ---- workspace ----
#define XS_OFF    0
#define XS_BYTES  (BATCH*HP*HP*CIN*2)
#define WT_OFF    (XS_OFF + XS_BYTES)
#define WT_BYTES  (9*COUT*CIN*2)
#define ISG_OFF   (WT_OFF + WT_BYTES)

// ---------- fused prep: blocks [0,544) pack xs, blocks [544,1056) prep weights+isg ----------
__global__ __launch_bounds__(256)
void prep_all(const float* __restrict__ x, const float* __restrict__ s,
              const float* __restrict__ w,
              __hip_bfloat16* __restrict__ xs, __hip_bfloat16* __restrict__ wt,
              float* __restrict__ isg) {
  __shared__ __align__(16) char smem[35328];
  const int bid = blockIdx.x;
  const int tid = threadIdx.x;

  if (bid < BATCH * 34) {
    // ---- pack role: xs[b][hp][wp][i] = bf16(s[b,i]*x[b,i,hp-1,wp-1]), borders zero ----
    unsigned short (*tile)[520] = (unsigned short (*)[520])smem;   // 33280 B
    float* ssh = (float*)(smem + 33280);                           // 2048 B
    const int hp = bid % 34;
    const int b  = bid / 34;
    __hip_bfloat16* rowbase = xs + (((size_t)(b * HP + hp)) * HP) * CIN;

    if (hp == 0 || hp == 33) {
      for (int j = tid; j < HP * CIN / 8; j += 256)
        ((int4*)rowbase)[j] = make_int4(0, 0, 0, 0);
      return;
    }
    if (tid < 64)        ((int4*)rowbase)[tid] = make_int4(0, 0, 0, 0);
    else if (tid < 128)  ((int4*)(rowbase + 33 * CIN))[tid - 64] = make_int4(0, 0, 0, 0);

    ssh[tid]       = s[b * CIN + tid];
    ssh[256 + tid] = s[b * CIN + 256 + tid];
    __syncthreads();

    const int h = hp - 1;
    const int r = tid >> 3;
    const int c = tid & 7;
    const float* xbase = x + (size_t)b * CIN * HWN + h * WW;
#pragma unroll
    for (int p = 0; p < 16; ++p) {
      int i = p * 32 + r;
      float4 v = *(const float4*)(xbase + (size_t)i * HWN + c * 4);
      float sc = ssh[i];
#pragma unroll
      for (int j = 0; j < 4; ++j) {
        float f = ((const float*)&v)[j] * sc;
        __hip_bfloat16 hb = __float2bfloat16(f);
        tile[c * 4 + j][i] = *(unsigned short*)&hb;
      }
    }
    __syncthreads();

    const int wq = tid >> 3;
    const int i0 = (tid & 7) * 64;
    __hip_bfloat16* dst = rowbase + (wq + 1) * CIN + i0;
    const int4* src = (const int4*)&tile[wq][i0];
#pragma unroll
    for (int q = 0; q < 8; ++q)
      ((int4*)dst)[q] = src[q];
  } else {
    // ---- weight role: Wt[k][o][i]=bf16(w[o,i,k]); isg[b,o]=rsqrt(sum s^2*wsq+eps) ----
    float* s2  = (float*)smem;                 // 32768 B
    float (*red)[4] = (float (*)[4])(smem + 32768);
    const int o = bid - BATCH * 34;
    for (int j = tid; j < BATCH * CIN; j += 256) {
      float v = s[j];
      s2[j] = v * v;
    }
    float ss[2];
#pragma unroll
    for (int u = 0; u < 2; ++u) {
      int i = tid + u * 256;
      const float* wp = w + ((size_t)o * CIN + i) * 9;
      float acc = 0.f;
#pragma unroll
      for (int k = 0; k < 9; ++k) {
        float v = wp[k];
        acc += v * v;
        wt[(size_t)k * COUT * CIN + o * CIN + i] = __float2bfloat16(v);
      }
      ss[u] = acc;
    }
    __syncthreads();
    float accb[16];
#pragma unroll
    for (int b = 0; b < 16; ++b) accb[b] = 0.f;
#pragma unroll
    for (int u = 0; u < 2; ++u) {
      int i = tid + u * 256;
      float q = ss[u];
#pragma unroll
      for (int b = 0; b < 16; ++b) accb[b] += q * s2[b * CIN + i];
    }
#pragma unroll
    for (int b = 0; b < 16; ++b) {
#pragma unroll
      for (int off = 32; off; off >>= 1) accb[b] += __shfl_xor(accb[b], off);
      if ((tid & 63) == 0) red[b][tid >> 6] = accb[b];
    }
    __syncthreads();
    if (tid < 16) {
      float tot = red[tid][0] + red[tid][1] + red[tid][2] + red[tid][3];
      isg[tid * COUT + o] = 1.0f / sqrtf(tot + EPS_);
    }
  }
}

// ---------- conv: A direct-from-global (reg double-buffer), B via 3-slot LDS ----------
// BM=128, BN=256, BK=64; 8 waves 2Mx4N (64x64 each); 256 blocks (1/CU).
// Per tile: [load A(t+1) regs | stage B(t+2) slot | 2x(4 ds_read + 16 MFMA)]
// then lgkmcnt(0) + vmcnt(4) + barrier. vmcnt(4) keeps B(t+2) in flight;
// B(t) was certified at the end of tile t-1 (>=12 ops younger than it).
__global__ __launch_bounds__(512, 2)
void conv_v3(const __hip_bfloat16* __restrict__ xs,
             const __hip_bfloat16* __restrict__ wt,
             const float* __restrict__ isg,
             float* __restrict__ out) {
  extern __shared__ __align__(16) char ldsB[];

  const int bid = blockIdx.x;
  const int lin = (bid & 7) * 32 + (bid >> 3);   // XCD-contiguous
  const int b  = lin >> 4;
  const int mt = (lin >> 2) & 3;
  const int nt = lin & 3;
  const int m0  = mt * 128;
  const int hw0 = nt * 256;

  const int t  = threadIdx.x;
  const int wv = t >> 6;
  const int l  = t & 63;
  const int wr = wv >> 2;            // 0..1 M half
  const int wc = wv & 3;             // 0..3 N quarter

  // B staging bases (element offsets into spatial-shifted xs), swizzled source
  int baseB[4];
  const int swz = (l & 7) ^ (l >> 3);
#pragma unroll
  for (int q = 0; q < 4; ++q) {
    int r = (wv * 4 + q) * 8 + (l >> 3);
    int n_abs = hw0 + r;
    int hB = n_abs >> 5, wB = n_abs & 31;
    baseB[q] = ((b * HP + hB) * HP + wB) * CIN + swz * 8;
  }

  // B ds_read byte offsets within a slot (swizzle-matched; verified r2/r5)
  int offB[2][4];
#pragma unroll
  for (int kk = 0; kk < 2; ++kk)
#pragma unroll
    for (int f = 0; f < 4; ++f) {
      int slot16 = ((kk * 4) + (l >> 4)) ^ (l & 7);
      offB[kk][f] = (wc * 64 + f * 16 + (l & 15)) * 128 + slot16 * 16;
    }

  // A fragment element offsets within a tap/ic base
  int ark[2][4];
#pragma unroll
  for (int kk = 0; kk < 2; ++kk)
#pragma unroll
    for (int mf = 0; mf < 4; ++mf)
      ark[kk][mf] = (m0 + wr * 64 + mf * 16 + (l & 15)) * CIN + kk * 32 + (l >> 4) * 8;

  f32x4 acc[4][4];
#pragma unroll
  for (int m = 0; m < 4; ++m)
#pragma unroll
    for (int n = 0; n < 4; ++n)
      acc[m][n] = (f32x4){0.f, 0.f, 0.f, 0.f};

#define MF(a, bb, c) __builtin_amdgcn_mfma_f32_16x16x32_bf16(a, bb, c, 0, 0, 0)

#define STAGE_B(q, gB, sl)                                                  \
  __builtin_amdgcn_global_load_lds(                                         \
      (gvoid*)(const void*)(xs + (gB) + baseB[q]),                          \
      (lvoid*)(ldsB + (sl) * SLOTB + (wv * 4 + (q)) * 1024), 16, 0, 0)

#define LOAD_A(AN, tti)                                                     \
  {                                                                         \
    int tap_ = (tti) >> 3, ic_ = (tti) & 7;                                 \
    const __hip_bfloat16* ap_ = wt + (size_t)tap_ * (COUT * CIN) + ic_ * 64;\
    AN[0][0] = *(const bf16x8*)(ap_ + ark[0][0]);                           \
    AN[0][1] = *(const bf16x8*)(ap_ + ark[0][1]);                           \
    AN[0][2] = *(const bf16x8*)(ap_ + ark[0][2]);                           \
    AN[0][3] = *(const bf16x8*)(ap_ + ark[0][3]);                           \
    AN[1][0] = *(const bf16x8*)(ap_ + ark[1][0]);                           \
    AN[1][1] = *(const bf16x8*)(ap_ + ark[1][1]);                           \
    AN[1][2] = *(const bf16x8*)(ap_ + ark[1][2]);                           \
    AN[1][3] = *(const bf16x8*)(ap_ + ark[1][3]);                           \
  }

#define STAGE_TILE_B(tti, sl)                                               \
  {                                                                         \
    int tap_ = (tti) >> 3, ic_ = (tti) & 7;                                 \
    int kh_ = tap_ / 3, kw_ = tap_ - kh_ * 3;                               \
    int gB_ = (kh_ * HP + kw_) * CIN + ic_ * 64;                            \
    STAGE_B(0, gB_, sl); STAGE_B(1, gB_, sl);                               \
    STAGE_B(2, gB_, sl); STAGE_B(3, gB_, sl);                               \
  }

#define KK_PHASE(kk, AC)                                                    \
  {                                                                         \
    bf16x8 b0 = *(const bf16x8*)(pB + offB[kk][0]);                         \
    bf16x8 b1 = *(const bf16x8*)(pB + offB[kk][1]);                         \
    bf16x8 b2 = *(const bf16x8*)(pB + offB[kk][2]);                         \
    bf16x8 b3 = *(const bf16x8*)(pB + offB[kk][3]);                         \
    __builtin_amdgcn_s_setprio(1);                                          \
    acc[0][0] = MF(AC[kk][0], b0, acc[0][0]);                               \
    acc[0][1] = MF(AC[kk][0], b1, acc[0][1]);                               \
    acc[0][2] = MF(AC[kk][0], b2, acc[0][2]);                               \
    acc[0][3] = MF(AC[kk][0], b3, acc[0][3]);                               \
    acc[1][0] = MF(AC[kk][1], b0, acc[1][0]);                               \
    acc[1][1] = MF(AC[kk][1], b1, acc[1][1]);                               \
    acc[1][2] = MF(AC[kk][1], b2, acc[1][2]);                               \
    acc[1][3] = MF(AC[kk][1], b3, acc[1][3]);                               \
    acc[2][0] = MF(AC[kk][2], b0, acc[2][0]);                               \
    acc[2][1] = MF(AC[kk][2], b1, acc[2][1]);                               \
    acc[2][2] = MF(AC[kk][2], b2, acc[2][2]);                               \
    acc[2][3] = MF(AC[kk][2], b3, acc[2][3]);                               \
    acc[3][0] = MF(AC[kk][3], b0, acc[3][0]);                               \
    acc[3][1] = MF(AC[kk][3], b1, acc[3][1]);                               \
    acc[3][2] = MF(AC[kk][3], b2, acc[3][2]);                               \
    acc[3][3] = MF(AC[kk][3], b3, acc[3][3]);                               \
    __builtin_amdgcn_s_setprio(0);                                          \
  }

#define TILE(AC, AN, tt)                                                    \
  {                                                                         \
    int t1 = (tt) + 1; if (t1 >= NTILES) t1 = NTILES - 1;                   \
    int t2 = (tt) + 2; if (t2 >= NTILES) t2 = NTILES - 1;                   \
    LOAD_A(AN, t1);                                                         \
    STAGE_TILE_B(t2, sl2);                                                  \
    const char* pB = ldsB + cur * SLOTB;                                    \
    KK_PHASE(0, AC);                                                        \
    KK_PHASE(1, AC);                                                        \
    asm volatile("s_waitcnt lgkmcnt(0)" ::: "memory");                      \
    asm volatile("s_waitcnt vmcnt(4)" ::: "memory");                        \
    __builtin_amdgcn_sched_barrier(0);                                      \
    __builtin_amdgcn_s_barrier();                                           \
    __builtin_amdgcn_sched_barrier(0);                                      \
    cur = (cur == 2) ? 0 : cur + 1;                                         \
    sl2 = (sl2 == 2) ? 0 : sl2 + 1;                                         \
  }

  bf16x8 a0[2][4], a1[2][4];
  // prologue: B(0)->slot0, B(1)->slot1, A(0)->a0
  STAGE_TILE_B(0, 0);
  STAGE_TILE_B(1, 1);
  LOAD_A(a0, 0);
  asm volatile("s_waitcnt vmcnt(4)" ::: "memory");
  __builtin_amdgcn_sched_barrier(0);
  __builtin_amdgcn_s_barrier();
  __builtin_amdgcn_sched_barrier(0);

  int cur = 0, sl2 = 2;
#pragma unroll 1
  for (int tt = 0; tt < NTILES; tt += 2) {
    TILE(a0, a1, tt);
    TILE(a1, a0, tt + 1);
  }
  asm volatile("s_waitcnt vmcnt(0)" ::: "memory");

  // epilogue: C/D col=l&15 -> hw, row=(l>>4)*4+j -> o
#pragma unroll
  for (int m = 0; m < 4; ++m) {
#pragma unroll
    for (int j = 0; j < 4; ++j) {
      int o = m0 + wr * 64 + m * 16 + (l >> 4) * 4 + j;
      float sg = isg[b * COUT + o];
      float* orow = out + ((size_t)(b * COUT + o)) * HWN + hw0 + wc * 64 + (l & 15);
#pragma unroll
      for (int n = 0; n < 4; ++n)
        orow[n * 16] = acc[m][n][j] * sg;
    }
  }
}

extern "C" void kernel_launch(void* const* d_in, const int* in_sizes, int n_in,
                              void* d_out, int out_size, void* d_ws, size_t ws_size,
                              hipStream_t stream) {
  const float* x = (const float*)d_in[0];
  const float* s = (const float*)d_in[1];
  const float* w = (const float*)d_in[2];
  float* out = (float*)d_out;
  char* ws = (char*)d_ws;
  __hip_bfloat16* xs  = (__hip_bfloat16*)(ws + XS_OFF);
  __hip_bfloat16* wt  = (__hip_bfloat16*)(ws + WT_OFF);
  float*          isg = (float*)(ws + ISG_OFF);

  (void)hipFuncSetAttribute((const void*)conv_v3,
                            hipFuncAttributeMaxDynamicSharedMemorySize, LDS_BYTES);

  hipLaunchKernelGGL(prep_all, dim3(BATCH * 34 + COUT), dim3(256), 0, stream,
                     x, s, w, xs, wt, isg);
  hipLaunchKernelGGL(conv_v3, dim3(256), dim3(512), LDS_BYTES, stream,
                     xs, wt, isg, out);
}

// Round 8
// 166.994 us; speedup vs baseline: 1.6572x; 1.6572x over previous
//
#include <hip/hip_runtime.h>
#include <hip/hip_bf16.h>
#include <stdint.h>

#define BATCH 16
#define CIN   512
#define COUT  512
#define HH    32
#define WW    32
#define HP    34
#define HWN   1024
#define EPS_  1e-8f

#define NTILES 72               // 9 taps * 8 ic-chunks, BK=64
#define BUFBYTES 32768          // A 16KB + B 16KB per buffer
#define LDS_BYTES (2*BUFBYTES)  // 64 KB -> 2 blocks/CU

typedef __attribute__((ext_vector_type(8))) short bf16x8;
typedef __attribute__((ext_vector_type(4))) float f32x4;
typedef __attribute__((address_space(1))) void gvoid;
typedef __attribute__((address_space(3))) void lvoid;

// ---- workspace ----
#define XS_OFF    0
#define XS_BYTES  (BATCH*HP*HP*CIN*2)
#define WT_OFF    (XS_OFF + XS_BYTES)
#define WT_BYTES  (9*COUT*CIN*2)
#define ISG_OFF   (WT_OFF + WT_BYTES)

// ---------- fused prep: blocks [0,544) pack xs, blocks [544,1056) weights+isg ----------
__global__ __launch_bounds__(256)
void prep_all(const float* __restrict__ x, const float* __restrict__ s,
              const float* __restrict__ w,
              __hip_bfloat16* __restrict__ xs, __hip_bfloat16* __restrict__ wt,
              float* __restrict__ isg) {
  __shared__ __align__(16) char smem[35328];
  const int bid = blockIdx.x;
  const int tid = threadIdx.x;

  if (bid < BATCH * 34) {
    // ---- pack role: xs[b][hp][wp][i] = bf16(s[b,i]*x[b,i,hp-1,wp-1]), borders zero ----
    unsigned short (*tile)[520] = (unsigned short (*)[520])smem;   // 33280 B
    float* ssh = (float*)(smem + 33280);                           // 2048 B
    const int hp = bid % 34;
    const int b  = bid / 34;
    __hip_bfloat16* rowbase = xs + (((size_t)(b * HP + hp)) * HP) * CIN;

    if (hp == 0 || hp == 33) {
      for (int j = tid; j < HP * CIN / 8; j += 256)
        ((int4*)rowbase)[j] = make_int4(0, 0, 0, 0);
      return;
    }
    if (tid < 64)        ((int4*)rowbase)[tid] = make_int4(0, 0, 0, 0);
    else if (tid < 128)  ((int4*)(rowbase + 33 * CIN))[tid - 64] = make_int4(0, 0, 0, 0);

    ssh[tid]       = s[b * CIN + tid];
    ssh[256 + tid] = s[b * CIN + 256 + tid];
    __syncthreads();

    const int h = hp - 1;
    const int r = tid >> 3;
    const int c = tid & 7;
    const float* xbase = x + (size_t)b * CIN * HWN + h * WW;
#pragma unroll
    for (int p = 0; p < 16; ++p) {
      int i = p * 32 + r;
      float4 v = *(const float4*)(xbase + (size_t)i * HWN + c * 4);
      float sc = ssh[i];
#pragma unroll
      for (int j = 0; j < 4; ++j) {
        float f = ((const float*)&v)[j] * sc;
        __hip_bfloat16 hb = __float2bfloat16(f);
        tile[c * 4 + j][i] = *(unsigned short*)&hb;
      }
    }
    __syncthreads();

    const int wq = tid >> 3;
    const int i0 = (tid & 7) * 64;
    __hip_bfloat16* dst = rowbase + (wq + 1) * CIN + i0;
    const int4* src = (const int4*)&tile[wq][i0];
#pragma unroll
    for (int q = 0; q < 8; ++q)
      ((int4*)dst)[q] = src[q];
  } else {
    // ---- weight role: stage w row in LDS (coalesced), then convert+reduce ----
    const int o = bid - BATCH * 34;
    float* wrow = (float*)smem;                       // 4608 floats = 18432 B
    {
      const float4* wsrc = (const float4*)(w + (size_t)o * CIN * 9);
      float4* wdst = (float4*)wrow;
      for (int j = tid; j < CIN * 9 / 4; j += 256)    // 1152 float4, coalesced
        wdst[j] = wsrc[j];
    }
    __syncthreads();

    float ss[2];
#pragma unroll
    for (int u = 0; u < 2; ++u) {
      int i = tid + u * 256;
      float acc = 0.f;
#pragma unroll
      for (int k = 0; k < 9; ++k) {                   // stride-9 LDS: 2-way, free
        float v = wrow[i * 9 + k];
        acc += v * v;
        wt[(size_t)k * COUT * CIN + o * CIN + i] = __float2bfloat16(v);
      }
      ss[u] = acc;
    }
    __syncthreads();                                  // done with wrow

    float* s2 = (float*)smem;                         // 32768 B (reuse)
    float (*red)[4] = (float (*)[4])(smem + 32768);
    for (int j = tid; j < BATCH * CIN; j += 256) {
      float v = s[j];
      s2[j] = v * v;
    }
    __syncthreads();

    float accb[16];
#pragma unroll
    for (int b = 0; b < 16; ++b) accb[b] = 0.f;
#pragma unroll
    for (int u = 0; u < 2; ++u) {
      int i = tid + u * 256;
      float q = ss[u];
#pragma unroll
      for (int b = 0; b < 16; ++b) accb[b] += q * s2[b * CIN + i];
    }
#pragma unroll
    for (int b = 0; b < 16; ++b) {
#pragma unroll
      for (int off = 32; off; off >>= 1) accb[b] += __shfl_xor(accb[b], off);
      if ((tid & 63) == 0) red[b][tid >> 6] = accb[b];
    }
    __syncthreads();
    if (tid < 16) {
      float tot = red[tid][0] + red[tid][1] + red[tid][2] + red[tid][3];
      isg[tid * COUT + o] = 1.0f / sqrtf(tot + EPS_);
    }
  }
}

// ---------- conv: round-2 proven geometry + double-buffered prefetch (T3 minimum) ----------
// 128x128 tile, BK=64, 4 waves 2x2, 512 blocks (2/CU). Per tile:
// STAGE(t+1 -> buf^1) issued FIRST, then ds_read+32 MFMA on buf, then ONE
// __syncthreads() (its vmcnt(0)+lgkmcnt(0) drain lands AFTER compute, so the
// t+1 loads had the whole MFMA phase to complete). r2 had the drain BEFORE
// compute (latency exposed) and 2 barriers/tile.
__global__ __launch_bounds__(256, 2)
void conv_db(const __hip_bfloat16* __restrict__ xs,
             const __hip_bfloat16* __restrict__ wt,
             const float* __restrict__ isg,
             float* __restrict__ out) {
  extern __shared__ __align__(16) char lds[];

  const int bid = blockIdx.x;
  const int nt = bid & 7;
  const int mt = (bid >> 3) & 3;
  const int b  = bid >> 5;
  const int m0  = mt * 128;
  const int hw0 = nt * 128;

  const int t  = threadIdx.x;
  const int wv = t >> 6;
  const int l  = t & 63;
  const int wr = wv >> 1;
  const int wc = wv & 1;
  const int segbase = wv * 4;

  // staging bases (verified r2: swizzled global source, linear LDS dest)
  int baseA[4], baseB[4];
#pragma unroll
  for (int q = 0; q < 4; ++q) {
    int seg = segbase + q;
    int r = seg * 8 + (l >> 3);
    int swz = (l & 7) ^ (l >> 3);
    baseA[q] = (m0 + r) * CIN + swz * 8;
    int n_abs = hw0 + r;
    int hB = n_abs >> 5, wB = n_abs & 31;
    baseB[q] = ((b * HP + hB) * HP + wB) * CIN + swz * 8;
  }

  // ds_read byte offsets within a buffer (verified r2: 0 bank conflicts)
  int offA[2][4], offB[2][4];
#pragma unroll
  for (int kk = 0; kk < 2; ++kk) {
#pragma unroll
    for (int f = 0; f < 4; ++f) {
      int slot = ((kk * 4) + (l >> 4)) ^ (l & 7);
      offA[kk][f] = (wr * 64 + f * 16 + (l & 15)) * 128 + slot * 16;
      offB[kk][f] = (wc * 64 + f * 16 + (l & 15)) * 128 + slot * 16;
    }
  }

  f32x4 acc[4][4];
#pragma unroll
  for (int m = 0; m < 4; ++m)
#pragma unroll
    for (int n = 0; n < 4; ++n)
      acc[m][n] = (f32x4){0.f, 0.f, 0.f, 0.f};

#define TILE_OFFS(tt, gA, gB)                                   \
  {                                                             \
    int tap = (tt) >> 3, ic = (tt) & 7;                         \
    int kh = (tap * 11) >> 5;                                   \
    int kw = tap - kh * 3;                                      \
    gA = tap * (COUT * CIN) + ic * 64;                          \
    gB = (kh * HP + kw) * CIN + ic * 64;                        \
  }

#define STAGE(tt, buf)                                                      \
  {                                                                         \
    int gA_, gB_;                                                           \
    TILE_OFFS(tt, gA_, gB_);                                                \
    char* dA_ = lds + (buf) * BUFBYTES;                                     \
    char* dB_ = dA_ + 16384;                                                \
    _Pragma("unroll")                                                       \
    for (int q = 0; q < 4; ++q)                                             \
      __builtin_amdgcn_global_load_lds(                                     \
          (gvoid*)(const void*)(wt + gA_ + baseA[q]),                       \
          (lvoid*)(dA_ + (segbase + q) * 1024), 16, 0, 0);                  \
    _Pragma("unroll")                                                       \
    for (int q = 0; q < 4; ++q)                                             \
      __builtin_amdgcn_global_load_lds(                                     \
          (gvoid*)(const void*)(xs + gB_ + baseB[q]),                       \
          (lvoid*)(dB_ + (segbase + q) * 1024), 16, 0, 0);                  \
  }

  STAGE(0, 0);
  __syncthreads();

  int buf = 0;
#pragma unroll 1
  for (int tt = 0; tt < NTILES; ++tt) {
    if (tt + 1 < NTILES) STAGE(tt + 1, buf ^ 1);
    const char* pA = lds + buf * BUFBYTES;
    const char* pB = pA + 16384;
#pragma unroll
    for (int kk = 0; kk < 2; ++kk) {
      bf16x8 af[4], bfr[4];
#pragma unroll
      for (int f = 0; f < 4; ++f) af[f]  = *(const bf16x8*)(pA + offA[kk][f]);
#pragma unroll
      for (int f = 0; f < 4; ++f) bfr[f] = *(const bf16x8*)(pB + offB[kk][f]);
#pragma unroll
      for (int m = 0; m < 4; ++m)
#pragma unroll
        for (int n = 0; n < 4; ++n)
          acc[m][n] = __builtin_amdgcn_mfma_f32_16x16x32_bf16(
              af[m], bfr[n], acc[m][n], 0, 0, 0);
    }
    __syncthreads();    // drains vmcnt (t+1 stage) + lgkm AFTER compute
    buf ^= 1;
  }

  // epilogue: C/D col=l&15 -> hw, row=(l>>4)*4+j -> o  (verified r2)
#pragma unroll
  for (int m = 0; m < 4; ++m) {
#pragma unroll
    for (int j = 0; j < 4; ++j) {
      int o = m0 + wr * 64 + m * 16 + (l >> 4) * 4 + j;
      float sg = isg[b * COUT + o];
      float* orow = out + ((size_t)(b * COUT + o)) * HWN + hw0 + wc * 64 + (l & 15);
#pragma unroll
      for (int n = 0; n < 4; ++n)
        orow[n * 16] = acc[m][n][j] * sg;
    }
  }
}

extern "C" void kernel_launch(void* const* d_in, const int* in_sizes, int n_in,
                              void* d_out, int out_size, void* d_ws, size_t ws_size,
                              hipStream_t stream) {
  const float* x = (const float*)d_in[0];
  const float* s = (const float*)d_in[1];
  const float* w = (const float*)d_in[2];
  float* out = (float*)d_out;
  char* ws = (char*)d_ws;
  __hip_bfloat16* xs  = (__hip_bfloat16*)(ws + XS_OFF);
  __hip_bfloat16* wt  = (__hip_bfloat16*)(ws + WT_OFF);
  float*          isg = (float*)(ws + ISG_OFF);

  (void)hipFuncSetAttribute((const void*)conv_db,
                            hipFuncAttributeMaxDynamicSharedMemorySize, LDS_BYTES);

  hipLaunchKernelGGL(prep_all, dim3(BATCH * 34 + COUT), dim3(256), 0, stream,
                     x, s, w, xs, wt, isg);
  hipLaunchKernelGGL(conv_db, dim3(512), dim3(256), LDS_BYTES, stream,
                     xs, wt, isg, out);
}

// Round 9
// 164.333 us; speedup vs baseline: 1.6840x; 1.0162x over previous
//
#include <hip/hip_runtime.h>
#include <hip/hip_bf16.h>
#include <stdint.h>

#define BATCH 16
#define CIN   512
#define COUT  512
#define HH    32
#define WW    32
#define HP    34
#define HWN   1024
#define EPS_  1e-8f

#define NTILES 72               // 9 taps * 8 ic-chunks, BK=64
#define SLOT   16384            // one 128-row x 128B panel
#define LDS_BYTES (5*SLOT)      // A x2 + B x3 = 80 KB -> 2 blocks/CU (160 KB)

typedef __attribute__((ext_vector_type(8))) short bf16x8;
typedef __attribute__((ext_vector_type(4))) float f32x4;
typedef __attribute__((address_space(1))) void gvoid;
typedef __attribute__((address_space(3))) void lvoid;

// ---- workspace ----
#define XS_OFF    0
#define XS_BYTES  (BATCH*HP*HP*CIN*2)
#define WT_OFF    (XS_OFF + XS_BYTES)
#define WT_BYTES  (9*COUT*CIN*2)
#define ISG_OFF   (WT_OFF + WT_BYTES)

// ---------- fused prep: blocks [0,544) pack xs, blocks [544,1056) weights+isg ----------
// (pack role unchanged since r3; weight role reverted to r5 version — r8's
//  LDS-staged variant measured ~7 us slower on the 'rest' budget)
__global__ __launch_bounds__(256)
void prep_all(const float* __restrict__ x, const float* __restrict__ s,
              const float* __restrict__ w,
              __hip_bfloat16* __restrict__ xs, __hip_bfloat16* __restrict__ wt,
              float* __restrict__ isg) {
  __shared__ __align__(16) char smem[35328];
  const int bid = blockIdx.x;
  const int tid = threadIdx.x;

  if (bid < BATCH * 34) {
    unsigned short (*tile)[520] = (unsigned short (*)[520])smem;
    float* ssh = (float*)(smem + 33280);
    const int hp = bid % 34;
    const int b  = bid / 34;
    __hip_bfloat16* rowbase = xs + (((size_t)(b * HP + hp)) * HP) * CIN;

    if (hp == 0 || hp == 33) {
      for (int j = tid; j < HP * CIN / 8; j += 256)
        ((int4*)rowbase)[j] = make_int4(0, 0, 0, 0);
      return;
    }
    if (tid < 64)        ((int4*)rowbase)[tid] = make_int4(0, 0, 0, 0);
    else if (tid < 128)  ((int4*)(rowbase + 33 * CIN))[tid - 64] = make_int4(0, 0, 0, 0);

    ssh[tid]       = s[b * CIN + tid];
    ssh[256 + tid] = s[b * CIN + 256 + tid];
    __syncthreads();

    const int h = hp - 1;
    const int r = tid >> 3;
    const int c = tid & 7;
    const float* xbase = x + (size_t)b * CIN * HWN + h * WW;
#pragma unroll
    for (int p = 0; p < 16; ++p) {
      int i = p * 32 + r;
      float4 v = *(const float4*)(xbase + (size_t)i * HWN + c * 4);
      float sc = ssh[i];
#pragma unroll
      for (int j = 0; j < 4; ++j) {
        float f = ((const float*)&v)[j] * sc;
        __hip_bfloat16 hb = __float2bfloat16(f);
        tile[c * 4 + j][i] = *(unsigned short*)&hb;
      }
    }
    __syncthreads();

    const int wq = tid >> 3;
    const int i0 = (tid & 7) * 64;
    __hip_bfloat16* dst = rowbase + (wq + 1) * CIN + i0;
    const int4* src = (const int4*)&tile[wq][i0];
#pragma unroll
    for (int q = 0; q < 8; ++q)
      ((int4*)dst)[q] = src[q];
  } else {
    float* s2  = (float*)smem;                 // 32768 B
    float (*red)[4] = (float (*)[4])(smem + 32768);
    const int o = bid - BATCH * 34;
    for (int j = tid; j < BATCH * CIN; j += 256) {
      float v = s[j];
      s2[j] = v * v;
    }
    float ss[2];
#pragma unroll
    for (int u = 0; u < 2; ++u) {
      int i = tid + u * 256;
      const float* wp = w + ((size_t)o * CIN + i) * 9;
      float acc = 0.f;
#pragma unroll
      for (int k = 0; k < 9; ++k) {
        float v = wp[k];
        acc += v * v;
        wt[(size_t)k * COUT * CIN + o * CIN + i] = __float2bfloat16(v);
      }
      ss[u] = acc;
    }
    __syncthreads();
    float accb[16];
#pragma unroll
    for (int b = 0; b < 16; ++b) accb[b] = 0.f;
#pragma unroll
    for (int u = 0; u < 2; ++u) {
      int i = tid + u * 256;
      float q = ss[u];
#pragma unroll
      for (int b = 0; b < 16; ++b) accb[b] += q * s2[b * CIN + i];
    }
#pragma unroll
    for (int b = 0; b < 16; ++b) {
#pragma unroll
      for (int off = 32; off; off >>= 1) accb[b] += __shfl_xor(accb[b], off);
      if ((tid & 63) == 0) red[b][tid >> 6] = accb[b];
    }
    __syncthreads();
    if (tid < 16) {
      float tot = red[tid][0] + red[tid][1] + red[tid][2] + red[tid][3];
      isg[tid * COUT + o] = 1.0f / sqrtf(tot + EPS_);
    }
  }
}

// ---------- conv: r8 geometry + counted vmcnt (T4) via asymmetric buffering ----------
// 128x128, BK=64, 4 waves 2x2, 512 blocks (2/CU). A double-buffered (1-tile
// slack, wt is L2-hot), B triple-buffered staged 2 tiles ahead (2-tile slack,
// xs is the HBM-missing stream). Per tile: issue A(t+1), B(t+2); 32 MFMA;
// lgkmcnt(0) + vmcnt(4) (leaves exactly B(t+2) in flight — never drains to 0)
// + raw s_barrier. Tail stays count-uniform via clamped re-stages into dead slots.
__global__ __launch_bounds__(256, 2)
void conv_cnt(const __hip_bfloat16* __restrict__ xs,
              const __hip_bfloat16* __restrict__ wt,
              const float* __restrict__ isg,
              float* __restrict__ out) {
  extern __shared__ __align__(16) char lds[];
  char* ldsA = lds;              // 2 x 16 KB
  char* ldsB = lds + 2 * SLOT;   // 3 x 16 KB

  const int bid = blockIdx.x;
  const int nt = bid & 7;
  const int mt = (bid >> 3) & 3;
  const int b  = bid >> 5;
  const int m0  = mt * 128;
  const int hw0 = nt * 128;

  const int t  = threadIdx.x;
  const int wv = t >> 6;
  const int l  = t & 63;
  const int wr = wv >> 1;
  const int wc = wv & 1;
  const int segbase = wv * 4;

  // staging bases (verified r2/r8: swizzled global source, linear LDS dest)
  int baseA[4], baseB[4];
#pragma unroll
  for (int q = 0; q < 4; ++q) {
    int seg = segbase + q;
    int r = seg * 8 + (l >> 3);
    int swz = (l & 7) ^ (l >> 3);
    baseA[q] = (m0 + r) * CIN + swz * 8;
    int n_abs = hw0 + r;
    int hB = n_abs >> 5, wB = n_abs & 31;
    baseB[q] = ((b * HP + hB) * HP + wB) * CIN + swz * 8;
  }

  // ds_read byte offsets within a slot (verified: 0 bank conflicts)
  int offA[2][4], offB[2][4];
#pragma unroll
  for (int kk = 0; kk < 2; ++kk) {
#pragma unroll
    for (int f = 0; f < 4; ++f) {
      int slot = ((kk * 4) + (l >> 4)) ^ (l & 7);
      offA[kk][f] = (wr * 64 + f * 16 + (l & 15)) * 128 + slot * 16;
      offB[kk][f] = (wc * 64 + f * 16 + (l & 15)) * 128 + slot * 16;
    }
  }

  f32x4 acc[4][4];
#pragma unroll
  for (int m = 0; m < 4; ++m)
#pragma unroll
    for (int n = 0; n < 4; ++n)
      acc[m][n] = (f32x4){0.f, 0.f, 0.f, 0.f};

  // clamp source tile (content harmless) but keep slot from UNclamped index,
  // so the vmcnt ledger stays uniform through the tail.
#define STAGE_A(tt, sl)                                                     \
  {                                                                         \
    int tc_ = (tt) < NTILES ? (tt) : NTILES - 1;                            \
    int tap_ = tc_ >> 3, ic_ = tc_ & 7;                                     \
    int gA_ = tap_ * (COUT * CIN) + ic_ * 64;                               \
    char* dA_ = ldsA + (sl) * SLOT;                                         \
    _Pragma("unroll")                                                       \
    for (int q = 0; q < 4; ++q)                                             \
      __builtin_amdgcn_global_load_lds(                                     \
          (gvoid*)(const void*)(wt + gA_ + baseA[q]),                       \
          (lvoid*)(dA_ + (segbase + q) * 1024), 16, 0, 0);                  \
  }

#define STAGE_B(tt, sl)                                                     \
  {                                                                         \
    int tc_ = (tt) < NTILES ? (tt) : NTILES - 1;                            \
    int tap_ = tc_ >> 3, ic_ = tc_ & 7;                                     \
    int kh_ = (tap_ * 11) >> 5;                                             \
    int kw_ = tap_ - kh_ * 3;                                               \
    int gB_ = (kh_ * HP + kw_) * CIN + ic_ * 64;                            \
    char* dB_ = ldsB + (sl) * SLOT;                                         \
    _Pragma("unroll")                                                       \
    for (int q = 0; q < 4; ++q)                                             \
      __builtin_amdgcn_global_load_lds(                                     \
          (gvoid*)(const void*)(xs + gB_ + baseB[q]),                       \
          (lvoid*)(dB_ + (segbase + q) * 1024), 16, 0, 0);                  \
  }

#define KK_PHASE(kk, pA, pB)                                                \
  {                                                                         \
    bf16x8 af[4], bfr[4];                                                   \
    _Pragma("unroll")                                                       \
    for (int f = 0; f < 4; ++f) af[f]  = *(const bf16x8*)((pA) + offA[kk][f]); \
    _Pragma("unroll")                                                       \
    for (int f = 0; f < 4; ++f) bfr[f] = *(const bf16x8*)((pB) + offB[kk][f]); \
    __builtin_amdgcn_s_setprio(1);                                          \
    _Pragma("unroll")                                                       \
    for (int m = 0; m < 4; ++m)                                             \
      _Pragma("unroll")                                                     \
      for (int n = 0; n < 4; ++n)                                           \
        acc[m][n] = __builtin_amdgcn_mfma_f32_16x16x32_bf16(                \
            af[m], bfr[n], acc[m][n], 0, 0, 0);                             \
    __builtin_amdgcn_s_setprio(0);                                          \
  }

  // prologue ledger: issue B(0)[4], A(0)[4], B(1)[4]; vmcnt(4) retires
  // B(0)+A(0), leaves B(1) in flight — matches steady-state invariant.
  STAGE_B(0, 0);
  STAGE_A(0, 0);
  STAGE_B(1, 1);
  asm volatile("s_waitcnt vmcnt(4)" ::: "memory");
  __builtin_amdgcn_sched_barrier(0);
  __builtin_amdgcn_s_barrier();
  __builtin_amdgcn_sched_barrier(0);

  int bB = 0;        // B slot for tile tt  (= tt % 3)
  int sB2 = 2;       // B slot for tile tt+2
#pragma unroll 1
  for (int tt = 0; tt < NTILES; ++tt) {
    STAGE_A(tt + 1, (tt + 1) & 1);
    const char* pA = ldsA + (tt & 1) * SLOT;
    const char* pB = ldsB + bB * SLOT;
    KK_PHASE(0, pA, pB);
    STAGE_B(tt + 2, sB2);
    KK_PHASE(1, pA, pB);
    // per-tile: outstanding = B(t+1)[4] + A(t+1)[4] + B(t+2)[4] = 12;
    // vmcnt(4) leaves only B(t+2) -> A(t+1), B(t+1) certified for next tile.
    asm volatile("s_waitcnt lgkmcnt(0)" ::: "memory");
    asm volatile("s_waitcnt vmcnt(4)" ::: "memory");
    __builtin_amdgcn_sched_barrier(0);
    __builtin_amdgcn_s_barrier();
    __builtin_amdgcn_sched_barrier(0);
    bB  = (bB  == 2) ? 0 : bB + 1;
    sB2 = (sB2 == 2) ? 0 : sB2 + 1;
  }
  asm volatile("s_waitcnt vmcnt(0)" ::: "memory");

  // epilogue: C/D col=l&15 -> hw, row=(l>>4)*4+j -> o  (verified r2)
#pragma unroll
  for (int m = 0; m < 4; ++m) {
#pragma unroll
    for (int j = 0; j < 4; ++j) {
      int o = m0 + wr * 64 + m * 16 + (l >> 4) * 4 + j;
      float sg = isg[b * COUT + o];
      float* orow = out + ((size_t)(b * COUT + o)) * HWN + hw0 + wc * 64 + (l & 15);
#pragma unroll
      for (int n = 0; n < 4; ++n)
        orow[n * 16] = acc[m][n][j] * sg;
    }
  }
}

extern "C" void kernel_launch(void* const* d_in, const int* in_sizes, int n_in,
                              void* d_out, int out_size, void* d_ws, size_t ws_size,
                              hipStream_t stream) {
  const float* x = (const float*)d_in[0];
  const float* s = (const float*)d_in[1];
  const float* w = (const float*)d_in[2];
  float* out = (float*)d_out;
  char* ws = (char*)d_ws;
  __hip_bfloat16* xs  = (__hip_bfloat16*)(ws + XS_OFF);
  __hip_bfloat16* wt  = (__hip_bfloat16*)(ws + WT_OFF);
  float*          isg = (float*)(ws + ISG_OFF);

  (void)hipFuncSetAttribute((const void*)conv_cnt,
                            hipFuncAttributeMaxDynamicSharedMemorySize, LDS_BYTES);

  hipLaunchKernelGGL(prep_all, dim3(BATCH * 34 + COUT), dim3(256), 0, stream,
                     x, s, w, xs, wt, isg);
  hipLaunchKernelGGL(conv_cnt, dim3(512), dim3(256), LDS_BYTES, stream,
                     xs, wt, isg, out);
}